// Round 2
// baseline (456.095 us; speedup 1.0000x reference)
//
#include <hip/hip_runtime.h>

// LightGCN propagation on MI355X — CSR-gather formulation (no float atomics
// in the hot loop).
// N = 150000 nodes, D = 64, E = 1.2M edges, 4 layers.
// d_out (= acc) accumulates sum of layer embeddings pre-scaled by 1/25.

#define DIMH 64
#define BLK 256
#define SCAN_ITEMS 8
#define SCAN_CHUNK (BLK * SCAN_ITEMS)  // 2048 elements per scan block

// ---------------------------------------------------------------------------
// init: embA = concat(user, item); acc = embA/25. float4-vectorized.
__global__ void k_init(const float* __restrict__ uemb, const float* __restrict__ iemb,
                       float* __restrict__ embA, float* __restrict__ acc,
                       long uElems, long totalElems) {
    long base = ((long)blockIdx.x * BLK + threadIdx.x) * 4;
    if (base >= totalElems) return;
    float4 v = (base < uElems) ? *(const float4*)(uemb + base)
                               : *(const float4*)(iemb + (base - uElems));
    *(float4*)(embA + base) = v;
    const float s = 1.0f / 25.0f;
    *(float4*)(acc + base) = make_float4(v.x * s, v.y * s, v.z * s, v.w * s);
}

// dst-degree histogram (int atomics).
__global__ void k_deg(const int* __restrict__ col, int* __restrict__ cnt, long E) {
    long e = (long)blockIdx.x * BLK + threadIdx.x;
    if (e < E) atomicAdd(&cnt[col[e]], 1);
}

// dinv[n] = cnt[n] > 0 ? rsqrt(cnt[n]) : 0
__global__ void k_dinv(const int* __restrict__ cnt, float* __restrict__ dinv, long N) {
    long n = (long)blockIdx.x * BLK + threadIdx.x;
    if (n < N) {
        int d = cnt[n];
        dinv[n] = (d > 0) ? rsqrtf((float)d) : 0.0f;
    }
}

// --- hierarchical exclusive scan of cnt[N] -> rowptr[N+1] ------------------
// pass 1: per-block sums
__global__ void k_scan_partial(const int* __restrict__ cnt, int* __restrict__ bsum, long N) {
    __shared__ int lds[BLK];
    long base = (long)blockIdx.x * SCAN_CHUNK + (long)threadIdx.x * SCAN_ITEMS;
    int tsum = 0;
    for (int i = 0; i < SCAN_ITEMS; ++i) {
        long idx = base + i;
        tsum += (idx < N) ? cnt[idx] : 0;
    }
    lds[threadIdx.x] = tsum;
    __syncthreads();
    for (int off = BLK / 2; off > 0; off >>= 1) {
        if (threadIdx.x < off) lds[threadIdx.x] += lds[threadIdx.x + off];
        __syncthreads();
    }
    if (threadIdx.x == 0) bsum[blockIdx.x] = lds[0];
}

// pass 2: single-block exclusive scan of block sums (nb <= 128); also writes
// rowptr[N] = E.
__global__ void k_scan_bsums(const int* __restrict__ bsum, int* __restrict__ boff,
                             int nb, int* __restrict__ rowptrN, int E) {
    __shared__ int lds[128];
    int t = threadIdx.x;
    int v = (t < nb) ? bsum[t] : 0;
    lds[t] = v;
    __syncthreads();
    for (int off = 1; off < 128; off <<= 1) {
        int mine = lds[t];
        int add = (t >= off) ? lds[t - off] : 0;
        __syncthreads();
        lds[t] = mine + add;
        __syncthreads();
    }
    int excl = (t > 0) ? lds[t - 1] : 0;
    if (t < nb) boff[t] = excl;
    if (t == 0) *rowptrN = E;
}

// pass 3: per-element exclusive scan + block offset
__global__ void k_scan_write(const int* __restrict__ cnt, const int* __restrict__ boff,
                             int* __restrict__ rowptr, long N) {
    __shared__ int lds[BLK];
    long base = (long)blockIdx.x * SCAN_CHUNK + (long)threadIdx.x * SCAN_ITEMS;
    int v[SCAN_ITEMS];
    int tsum = 0;
    for (int i = 0; i < SCAN_ITEMS; ++i) {
        long idx = base + i;
        v[i] = (idx < N) ? cnt[idx] : 0;
        tsum += v[i];
    }
    lds[threadIdx.x] = tsum;
    __syncthreads();
    for (int off = 1; off < BLK; off <<= 1) {
        int mine = lds[threadIdx.x];
        int add = (threadIdx.x >= off) ? lds[threadIdx.x - off] : 0;
        __syncthreads();
        lds[threadIdx.x] = mine + add;
        __syncthreads();
    }
    int run = boff[blockIdx.x] + ((threadIdx.x > 0) ? lds[threadIdx.x - 1] : 0);
    for (int i = 0; i < SCAN_ITEMS; ++i) {
        long idx = base + i;
        if (idx < N) rowptr[idx] = run;
        run += v[i];
    }
}

// fill CSR: edges[pos] = {src, bitcast(norm)}. Consumes cnt (atomicSub), so
// cnt must not be reused after this. Order within a segment is arbitrary.
__global__ void k_fill(const int* __restrict__ row, const int* __restrict__ col,
                       const float* __restrict__ dinv, const int* __restrict__ rowptr,
                       int* __restrict__ cnt, int2* __restrict__ edges, long E) {
    long e = (long)blockIdx.x * BLK + threadIdx.x;
    if (e >= E) return;
    int r = row[e];
    int c = col[e];
    float nrm = dinv[r] * dinv[c];
    int k = atomicSub(&cnt[c], 1) - 1;
    edges[rowptr[c] + k] = make_int2(r, __float_as_int(nrm));
}

// gather: 16 lanes per dst node; each lane owns a float4 slice of the 64-dim
// row. nxt[dst] = sum(norm * cur[src]); acc[dst] += nxt[dst]/25 (fused).
__global__ void k_gather(const float* __restrict__ cur, float* __restrict__ nxt,
                         float* __restrict__ acc,
                         const int* __restrict__ rowptr, const int2* __restrict__ edges,
                         long N, int storeNxt) {
    long g = (long)blockIdx.x * BLK + threadIdx.x;
    long node = g >> 4;
    if (node >= N) return;
    int q = (int)(g & 15);

    int beg = rowptr[node];
    int end = rowptr[node + 1];

    float4 s = make_float4(0.f, 0.f, 0.f, 0.f);
    for (int base = beg; base < end; base += 16) {
        int me = base + q;
        int2 p = (me < end) ? edges[me] : make_int2(0, 0);
        int n = end - base;
        if (n > 16) n = 16;
        for (int j = 0; j < n; ++j) {
            int src = __shfl(p.x, j, 16);
            float nrm = __int_as_float(__shfl(p.y, j, 16));
            float4 v = *(const float4*)(cur + (long)src * DIMH + q * 4);
            s.x += nrm * v.x;
            s.y += nrm * v.y;
            s.z += nrm * v.z;
            s.w += nrm * v.w;
        }
    }

    long off = node * DIMH + q * 4;
    if (storeNxt) *(float4*)(nxt + off) = s;
    const float sc = 1.0f / 25.0f;
    float4 a = *(float4*)(acc + off);
    a.x += s.x * sc; a.y += s.y * sc; a.z += s.z * sc; a.w += s.w * sc;
    *(float4*)(acc + off) = a;
}

// ---------------------------------------------------------------------------
extern "C" void kernel_launch(void* const* d_in, const int* in_sizes, int n_in,
                              void* d_out, int out_size, void* d_ws, size_t ws_size,
                              hipStream_t stream) {
    const float* uemb = (const float*)d_in[0];
    const float* iemb = (const float*)d_in[1];
    const int*   edge = (const int*)d_in[2];

    const long uElems = in_sizes[0];          // 100000*64
    const long iElems = in_sizes[1];          // 50000*64
    const long E      = in_sizes[2] / 2;      // 1200000
    const long total  = uElems + iElems;      // N*64
    const long N      = total / DIMH;         // 150000

    const int* row = edge;      // edge_index[0] = src
    const int* col = edge + E;  // edge_index[1] = dst

    float* acc = (float*)d_out;

    // workspace layout (keep every base 16B-aligned: pads are multiples of 64)
    const long Npad = (N + 63) & ~63L;
    int*   cnt    = (int*)d_ws;               // N ints (consumed by k_fill)
    int*   rowptr = cnt + Npad;               // N+1 ints
    int*   bsum   = rowptr + Npad + 64;       // <=128 ints
    int*   boff   = bsum + 128;               // <=128 ints
    float* dinv   = (float*)(boff + 128);     // N floats
    int2*  edges  = (int2*)(dinv + Npad);     // E packed {src, norm}
    float* embA   = (float*)(edges + E);      // N*64 floats
    float* embB   = embA + total;             // N*64 floats

    const int nb = (int)((N + SCAN_CHUNK - 1) / SCAN_CHUNK);  // 74 blocks

    hipMemsetAsync(cnt, 0, N * sizeof(int), stream);

    const long total4 = total / 4;
    k_init<<<(total4 + BLK - 1) / BLK, BLK, 0, stream>>>(uemb, iemb, embA, acc,
                                                         uElems, total);
    k_deg<<<(E + BLK - 1) / BLK, BLK, 0, stream>>>(col, cnt, E);
    k_dinv<<<(N + BLK - 1) / BLK, BLK, 0, stream>>>(cnt, dinv, N);
    k_scan_partial<<<nb, BLK, 0, stream>>>(cnt, bsum, N);
    k_scan_bsums<<<1, 128, 0, stream>>>(bsum, boff, nb, rowptr + N, (int)E);
    k_scan_write<<<nb, BLK, 0, stream>>>(cnt, boff, rowptr, N);
    k_fill<<<(E + BLK - 1) / BLK, BLK, 0, stream>>>(row, col, dinv, rowptr, cnt, edges, E);

    float* cur = embA;
    float* nxt = embB;
    const long gthreads = N * 16;
    for (int l = 0; l < 4; ++l) {
        k_gather<<<(gthreads + BLK - 1) / BLK, BLK, 0, stream>>>(
            cur, nxt, acc, rowptr, edges, N, (l < 3) ? 1 : 0);
        float* t = cur; cur = nxt; nxt = t;
    }
}